// Round 8
// baseline (262.096 us; speedup 1.0000x reference)
//
#include <hip/hip_runtime.h>
#include <hip/hip_bf16.h>

// SparseFactorisationDense: out = relu(scaling * (x @ (k0*m0) @ (k1*m1) @ (k2*m2)) + bias)
// B=8192, D=U=2048.
// R8 = R7 with 32x32x16 MFMA and 2 phases per K-tile (halves barrier count).
//   - v_mfma_f32_32x32x16_bf16, operand-swapped (D: 4 consecutive n per reg-quad)
//   - per phase: 12 ds_read_b128 + 2 half-tile stages + 16 MFMA, 2 barriers
//   - gates: vmcnt(4) at end of H0.B / H1.B (12 in flight, drain 8 = next tile)
//   - T1 XCD swizzle, slot-XOR LDS swizzle, gload_lds staging: as R7
//
// Stage ledger (iteration it, t1=2it+1, t2=2it+2, t3=2it+3):
//   H0.A (reads buf0-kh0): stage B(t1)h1,A(t1)h1 -> buf1-kh1 (last read it-1 H1.B)
//   H0.B (reads buf0-kh1): stage B(t2)h0,A(t2)h0 -> buf0-kh0 (read H0.A);  GATE vm4
//     in flight: [t1h1:4][t2h0:4] + [t1h0:4 from it-1 H1.B] = 12 -> drain t1 (8)
//   H1.A (reads buf1-kh0): stage B(t2)h1,A(t2)h1 -> buf0-kh1 (read H0.B)
//   H1.B (reads buf1-kh1): stage B(t3)h0,A(t3)h0 -> buf1-kh0 (read H1.A);  GATE vm4
//     in flight: [t2h0? drained][t2h1:4][t3h0:4]+[t2h0:4] = 12 -> drain t2 (8)
//   Every stage target's last read is >=1 barrier earlier (reader LGK0 before it).

typedef __attribute__((ext_vector_type(8)))  short  short8;
typedef __attribute__((ext_vector_type(8)))  ushort ushort8v;
typedef __attribute__((ext_vector_type(16))) float  f32x16;

#define KD 2048
#define ND 2048

__device__ __forceinline__ ushort f2b(float f) {      // fp32 -> bf16 RNE
    union { float f; unsigned u; } v; v.f = f;
    unsigned r = v.u + 0x7fffu + ((v.u >> 16) & 1u);
    return (ushort)(r >> 16);
}

__device__ __forceinline__ void gload16(const ushort* g, ushort* l) {
    __builtin_amdgcn_global_load_lds(
        (const __attribute__((address_space(1))) void*)g,
        (__attribute__((address_space(3))) void*)l, 16, 0, 0);
}

// ---- x: fp32 -> bf16, 8 elems/thread
__global__ __launch_bounds__(256)
void convx(const float* __restrict__ x, ushort* __restrict__ xb)
{
    const size_t i = (size_t)blockIdx.x * 256 + threadIdx.x;
    const float4* src = reinterpret_cast<const float4*>(x) + i * 2;
    const float4 f0 = src[0], f1 = src[1];
    ushort8v u;
    u[0]=f2b(f0.x); u[1]=f2b(f0.y); u[2]=f2b(f0.z); u[3]=f2b(f0.w);
    u[4]=f2b(f1.x); u[5]=f2b(f1.y); u[6]=f2b(f1.z); u[7]=f2b(f1.w);
    reinterpret_cast<ushort8v*>(xb)[i] = u;
}

// ---- masked-weight transpose+convert for all 3 layers (blockIdx.z picks layer)
__global__ __launch_bounds__(256)
void convT3(const float* __restrict__ k0w, const float* __restrict__ k1w,
            const float* __restrict__ k2w, const float* __restrict__ m0w,
            const float* __restrict__ m1w, const float* __restrict__ m2w,
            ushort* __restrict__ wbT)
{
    const int z = blockIdx.z;
    const float* kw = z == 0 ? k0w : (z == 1 ? k1w : k2w);
    const float* mw = z == 0 ? m0w : (z == 1 ? m1w : m2w);
    ushort* o = wbT + (size_t)z * KD * ND;

    __shared__ ushort t[32][36];
    const int tid = threadIdx.x;
    const int bk = blockIdx.x * 32, bn = blockIdx.y * 32;
    {
        const int r = tid >> 3, c = (tid & 7) * 4;
        const size_t g = (size_t)(bk + r) * ND + bn + c;
        const float4 kv = *reinterpret_cast<const float4*>(kw + g);
        const float4 mv = *reinterpret_cast<const float4*>(mw + g);
        t[r][c + 0] = f2b(kv.x * mv.x);
        t[r][c + 1] = f2b(kv.y * mv.y);
        t[r][c + 2] = f2b(kv.z * mv.z);
        t[r][c + 3] = f2b(kv.w * mv.w);
    }
    __syncthreads();
    {
        const int n = tid >> 3, kq = (tid & 7) * 4;
        ushort4 ov;
        ov.x = t[kq + 0][n]; ov.y = t[kq + 1][n];
        ov.z = t[kq + 2][n]; ov.w = t[kq + 3][n];
        *reinterpret_cast<ushort4*>(&o[(size_t)(bn + n) * KD + bk + kq]) = ov;
    }
}

// ================= 256x256 2-phase/K-tile GEMM (32x32x16 MFMA) =================
// C[M][N] = A[M][K] @ BT[N][K]^T, all bf16 in, fp32 accum.
template<int EPI>
__global__ __launch_bounds__(512, 2)
void gemm256(const ushort* __restrict__ A, const ushort* __restrict__ BT,
             void* __restrict__ Cout,
             const float* __restrict__ scaling, const float* __restrict__ bias)
{
    // [buf][op 0=A 1=B][kh][row*32 + k]  = 128 KiB
    __shared__ ushort S[2][2][2][256 * 32];

    const int tid  = threadIdx.x;
    const int lane = tid & 63;
    const int wid  = tid >> 6;                 // 0..7
    const int wr   = wid >> 2, wc = wid & 3;   // 2x4 wave grid: 128x64 per wave
    const int l31  = lane & 31;
    const int lh   = lane >> 5;                // k-half within fragment
    const int rk   = (l31 >> 1) & 3;           // read-side swizzle key
    // T1: bijective XCD swizzle (256 blocks % 8 XCDs == 0)
    const int id   = blockIdx.x;
    const int swz  = (id & 7) * 32 + (id >> 3);
    const int bn   = (swz & 7) * 256;          // 8 N-blocks
    const int bm   = (swz >> 3) * 256;         // 32 M-blocks
    const int srow = lane >> 2;                // staging: 16 rows / gload
    const int wrow = wid * 32;                 // this wave's 32-row staging slice
    // both-sides involution: physical 16B slot = logical slot ^ ((row>>1)&3)
    const int ssw  = ((lane & 3) ^ ((srow >> 1) & 3)) * 8;  // staged source k-off

    f32x16 acc[4][2] = {};

#define STAGE(op, bufl, kh, tile, G, g0) do {                                        \
    gload16(G + (size_t)((g0) + wrow + srow)      * KD + (tile)*64 + (kh)*32 + ssw,  \
            &S[bufl][op][kh][(wrow)      * 32]);                                     \
    gload16(G + (size_t)((g0) + wrow + 16 + srow) * KD + (tile)*64 + (kh)*32 + ssw,  \
            &S[bufl][op][kh][(wrow + 16) * 32]);                                     \
  } while (0)

#define BAR()  asm volatile("s_barrier" ::: "memory")
#define VM4()  asm volatile("s_waitcnt vmcnt(4)" ::: "memory")
#define VM0()  asm volatile("s_waitcnt vmcnt(0)" ::: "memory")
#define LGK0() asm volatile("s_waitcnt lgkmcnt(0)" ::: "memory")
#define SB()   __builtin_amdgcn_sched_barrier(0)
#define PRI1() __builtin_amdgcn_s_setprio(1)
#define PRI0() __builtin_amdgcn_s_setprio(0)

#define FA32(bufl, kh, mt, ks) (*(const short8*)&S[bufl][0][kh][ \
        (wr*128 + (mt)*32 + l31)*32 + ((((ks)*2 + lh) ^ rk) * 8)])
#define FB32(bufl, kh, nt, ks) (*(const short8*)&S[bufl][1][kh][ \
        (wc*64  + (nt)*32 + l31)*32 + ((((ks)*2 + lh) ^ rk) * 8)])

#define MF(a_, b_, c_) __builtin_amdgcn_mfma_f32_32x32x16_bf16(a_, b_, c_, 0, 0, 0)

// One phase: 12 ds_read_b128 + stages + BAR + 16 MFMA (operand-swapped) + BAR.
#define PH(bufl, kh, STG, GATE) do {                                                  \
    short8 a00=FA32(bufl,kh,0,0), a10=FA32(bufl,kh,1,0),                              \
           a20=FA32(bufl,kh,2,0), a30=FA32(bufl,kh,3,0);                              \
    short8 a01=FA32(bufl,kh,0,1), a11=FA32(bufl,kh,1,1),                              \
           a21=FA32(bufl,kh,2,1), a31=FA32(bufl,kh,3,1);                              \
    short8 b00=FB32(bufl,kh,0,0), b10=FB32(bufl,kh,1,0);                              \
    short8 b01=FB32(bufl,kh,0,1), b11=FB32(bufl,kh,1,1);                              \
    STG; BAR(); SB(); PRI1();                                                         \
    acc[0][0]=MF(b00,a00,acc[0][0]); acc[1][0]=MF(b00,a10,acc[1][0]);                 \
    acc[2][0]=MF(b00,a20,acc[2][0]); acc[3][0]=MF(b00,a30,acc[3][0]);                 \
    acc[0][1]=MF(b10,a00,acc[0][1]); acc[1][1]=MF(b10,a10,acc[1][1]);                 \
    acc[2][1]=MF(b10,a20,acc[2][1]); acc[3][1]=MF(b10,a30,acc[3][1]);                 \
    acc[0][0]=MF(b01,a01,acc[0][0]); acc[1][0]=MF(b01,a11,acc[1][0]);                 \
    acc[2][0]=MF(b01,a21,acc[2][0]); acc[3][0]=MF(b01,a31,acc[3][0]);                 \
    acc[0][1]=MF(b11,a01,acc[0][1]); acc[1][1]=MF(b11,a11,acc[1][1]);                 \
    acc[2][1]=MF(b11,a21,acc[2][1]); acc[3][1]=MF(b11,a31,acc[3][1]);                 \
    PRI0(); SB(); LGK0(); GATE; BAR();                                                \
  } while (0)

    // ---- prologue: t0 full (buf0, 4 stages) + t1 kh0 (buf1, 2 stages)
    STAGE(0, 0, 0, 0, A,  bm); STAGE(1, 0, 0, 0, BT, bn);
    STAGE(0, 0, 1, 0, A,  bm); STAGE(1, 0, 1, 0, BT, bn);
    STAGE(1, 1, 0, 1, BT, bn); STAGE(0, 1, 0, 1, A,  bm);
    VM4();   // drain t0's 8 loads; t1-kh0's 4 stay in flight
    BAR();

    const int NITER = KD / 128;                // 16
    for (int it = 0; it < NITER - 1; ++it) {
        const int t1 = 2 * it + 1, t2 = 2 * it + 2, t3 = 2 * it + 3;
        PH(0, 0, STAGE(1,1,1,t1,BT,bn); STAGE(0,1,1,t1,A,bm), );
        PH(0, 1, STAGE(1,0,0,t2,BT,bn); STAGE(0,0,0,t2,A,bm), VM4());
        PH(1, 0, STAGE(1,0,1,t2,BT,bn); STAGE(0,0,1,t2,A,bm), );
        PH(1, 1, STAGE(1,1,0,t3,BT,bn); STAGE(0,1,0,t3,A,bm), VM4());
    }
    // ---- tail: tiles 30 (buf0), 31 (buf1); only t31-kh1 still to stage
    PH(0, 0, STAGE(1,1,1,31,BT,bn); STAGE(0,1,1,31,A,bm), );
    PH(0, 1, , VM0());
    PH(1, 0, , );
    PH(1, 1, , );

    // ---- epilogue (swapped 32x32 layout): lane row m = l31;
    // reg-quad r -> n-cols nt*32 + lh*4 + r*8 + {0..3}
    const float sc = EPI ? scaling[0] : 0.f;
#pragma unroll
    for (int mt = 0; mt < 4; ++mt) {
        const size_t grow = (size_t)(bm + wr * 128 + mt * 32 + l31);
#pragma unroll
        for (int nt = 0; nt < 2; ++nt) {
#pragma unroll
            for (int r = 0; r < 4; ++r) {
                const int gcol = bn + wc * 64 + nt * 32 + lh * 4 + r * 8;
                if constexpr (EPI) {
                    const float4 bv = *reinterpret_cast<const float4*>(bias + gcol);
                    float4 v;
                    v.x = fmaxf(fmaf(sc, acc[mt][nt][4*r+0], bv.x), 0.f);
                    v.y = fmaxf(fmaf(sc, acc[mt][nt][4*r+1], bv.y), 0.f);
                    v.z = fmaxf(fmaf(sc, acc[mt][nt][4*r+2], bv.z), 0.f);
                    v.w = fmaxf(fmaf(sc, acc[mt][nt][4*r+3], bv.w), 0.f);
                    *reinterpret_cast<float4*>((float*)Cout + grow * ND + gcol) = v;
                } else {
                    ushort4 v;
                    v.x = f2b(acc[mt][nt][4*r+0]); v.y = f2b(acc[mt][nt][4*r+1]);
                    v.z = f2b(acc[mt][nt][4*r+2]); v.w = f2b(acc[mt][nt][4*r+3]);
                    *reinterpret_cast<ushort4*>((ushort*)Cout + grow * ND + gcol) = v;
                }
            }
        }
    }
#undef STAGE
#undef PH
#undef MF
#undef FA32
#undef FB32
}

extern "C" void kernel_launch(void* const* d_in, const int* in_sizes, int n_in,
                              void* d_out, int out_size, void* d_ws, size_t ws_size,
                              hipStream_t stream)
{
    // inputs: x, k0, k1, k2, m0, m1, m2, scaling, bias
    const float* x    = (const float*)d_in[0];
    const float* k0w  = (const float*)d_in[1];
    const float* k1w  = (const float*)d_in[2];
    const float* k2w  = (const float*)d_in[3];
    const float* m0w  = (const float*)d_in[4];
    const float* m1w  = (const float*)d_in[5];
    const float* m2w  = (const float*)d_in[6];
    const float* sc   = (const float*)d_in[7];
    const float* bias = (const float*)d_in[8];

    const int Md = in_sizes[0] / KD;               // 8192
    const size_t NE = (size_t)Md * KD;             // 16.7M elems

    // d_out (64MB fp32): [act1 bf16 32MB][x_bf16 32MB]; GEMM3 overwrites all.
    ushort* act1 = (ushort*)d_out;
    ushort* xb   = (ushort*)d_out + NE;
    float*  out  = (float*)d_out;
    // ws: [act2 bf16 32MB][wbT0 8MB][wbT1 8MB][wbT2 8MB] = 56MB
    ushort* act2 = (ushort*)d_ws;
    ushort* wbT  = (ushort*)d_ws + NE;

    dim3 bl(256);
    dim3 gX(NE / (256 * 8));                       // 8192
    dim3 gT(KD / 32, ND / 32, 3);                  // (64,64,3)
    dim3 gG((ND / 256) * (Md / 256)), bG(512);     // 256 blocks 1D (XCD swizzle inside)

    convx <<<gX, bl, 0, stream>>>(x, xb);
    convT3<<<gT, bl, 0, stream>>>(k0w, k1w, k2w, m0w, m1w, m2w, wbT);

    gemm256<0><<<gG, bG, 0, stream>>>(xb,   wbT,                     act1, nullptr, nullptr);
    gemm256<0><<<gG, bG, 0, stream>>>(act1, wbT + (size_t)KD * ND,     act2, nullptr, nullptr);
    gemm256<1><<<gG, bG, 0, stream>>>(act2, wbT + (size_t)2 * KD * ND, out,  sc, bias);
}

// Round 9
// 225.337 us; speedup vs baseline: 1.1631x; 1.1631x over previous
//
#include <hip/hip_runtime.h>
#include <hip/hip_bf16.h>

// SparseFactorisationDense: out = relu(scaling * (x @ (k0*m0) @ (k1*m1) @ (k2*m2)) + bias)
// B=8192, D=U=2048.
// R9 = R7 fragment pattern (16x16 MFMA, proven 0-conflict reads) + R8's merged
// phase structure (4 phases / 2 K-tiles instead of 8 -> half the barriers).
//   - phase: 12 ds_read_b128 (8 A + 4 B frags, one kh) + 2 half-tile stages
//            + 32 MFMA (operand-swapped) + 2 barriers
//   - gates: vmcnt(4) at P(0,1)/P(1,1) (12 in flight -> drain 8 = next tile)
//   - T1 XCD swizzle, slot-XOR LDS swizzle, gload_lds staging: as R7
//
// Stage ledger (iteration it, t1=2it+1, t2=2it+2, t3=2it+3):
//   P(0,0) reads buf0-kh0; stages t1h1 -> buf1-kh1 (last read: prev P(1,1))
//   P(0,1) reads buf0-kh1; stages t2h0 -> buf0-kh0 (read P(0,0)); VM4:
//     outstanding t1h0(4)+t1h1(4)+t2h0(4)=12 -> drains t1 fully (8)
//   P(1,0) reads buf1-kh0; stages t2h1 -> buf0-kh1 (read P(0,1))
//   P(1,1) reads buf1-kh1; stages t3h0 -> buf1-kh0 (read P(1,0)); VM4:
//     outstanding t2h0+t2h1+t3h0=12 -> drains t2 fully (8)
//   Every stage target's last read is >=1 barrier earlier (reader LGK0 first).

typedef __attribute__((ext_vector_type(8))) short  short8;
typedef __attribute__((ext_vector_type(8))) ushort ushort8v;
typedef __attribute__((ext_vector_type(4))) float  f32x4;

#define KD 2048
#define ND 2048

__device__ __forceinline__ ushort f2b(float f) {      // fp32 -> bf16 RNE
    union { float f; unsigned u; } v; v.f = f;
    unsigned r = v.u + 0x7fffu + ((v.u >> 16) & 1u);
    return (ushort)(r >> 16);
}

__device__ __forceinline__ void gload16(const ushort* g, ushort* l) {
    __builtin_amdgcn_global_load_lds(
        (const __attribute__((address_space(1))) void*)g,
        (__attribute__((address_space(3))) void*)l, 16, 0, 0);
}

// ---- x: fp32 -> bf16, 8 elems/thread
__global__ __launch_bounds__(256)
void convx(const float* __restrict__ x, ushort* __restrict__ xb)
{
    const size_t i = (size_t)blockIdx.x * 256 + threadIdx.x;
    const float4* src = reinterpret_cast<const float4*>(x) + i * 2;
    const float4 f0 = src[0], f1 = src[1];
    ushort8v u;
    u[0]=f2b(f0.x); u[1]=f2b(f0.y); u[2]=f2b(f0.z); u[3]=f2b(f0.w);
    u[4]=f2b(f1.x); u[5]=f2b(f1.y); u[6]=f2b(f1.z); u[7]=f2b(f1.w);
    reinterpret_cast<ushort8v*>(xb)[i] = u;
}

// ---- masked-weight transpose+convert for all 3 layers (blockIdx.z picks layer)
__global__ __launch_bounds__(256)
void convT3(const float* __restrict__ k0w, const float* __restrict__ k1w,
            const float* __restrict__ k2w, const float* __restrict__ m0w,
            const float* __restrict__ m1w, const float* __restrict__ m2w,
            ushort* __restrict__ wbT)
{
    const int z = blockIdx.z;
    const float* kw = z == 0 ? k0w : (z == 1 ? k1w : k2w);
    const float* mw = z == 0 ? m0w : (z == 1 ? m1w : m2w);
    ushort* o = wbT + (size_t)z * KD * ND;

    __shared__ ushort t[32][36];
    const int tid = threadIdx.x;
    const int bk = blockIdx.x * 32, bn = blockIdx.y * 32;
    {
        const int r = tid >> 3, c = (tid & 7) * 4;
        const size_t g = (size_t)(bk + r) * ND + bn + c;
        const float4 kv = *reinterpret_cast<const float4*>(kw + g);
        const float4 mv = *reinterpret_cast<const float4*>(mw + g);
        t[r][c + 0] = f2b(kv.x * mv.x);
        t[r][c + 1] = f2b(kv.y * mv.y);
        t[r][c + 2] = f2b(kv.z * mv.z);
        t[r][c + 3] = f2b(kv.w * mv.w);
    }
    __syncthreads();
    {
        const int n = tid >> 3, kq = (tid & 7) * 4;
        ushort4 ov;
        ov.x = t[kq + 0][n]; ov.y = t[kq + 1][n];
        ov.z = t[kq + 2][n]; ov.w = t[kq + 3][n];
        *reinterpret_cast<ushort4*>(&o[(size_t)(bn + n) * KD + bk + kq]) = ov;
    }
}

// ================= 256x256 merged-phase GEMM (16x16 MFMA) =================
// C[M][N] = A[M][K] @ BT[N][K]^T, all bf16 in, fp32 accum.
template<int EPI>
__global__ __launch_bounds__(512, 2)
void gemm256(const ushort* __restrict__ A, const ushort* __restrict__ BT,
             void* __restrict__ Cout,
             const float* __restrict__ scaling, const float* __restrict__ bias)
{
    // [buf][op 0=A 1=B][kh][row*32 + k]  = 128 KiB
    __shared__ ushort S[2][2][2][256 * 32];

    const int tid  = threadIdx.x;
    const int lane = tid & 63;
    const int wid  = tid >> 6;                 // 0..7
    const int wr   = wid >> 2, wc = wid & 3;   // 2x4 wave grid: 128x64 per wave
    const int l15  = lane & 15;
    const int kq   = lane >> 4;                // fragment k-slot 0..3
    // T1: bijective XCD swizzle (256 blocks % 8 XCDs == 0)
    const int id   = blockIdx.x;
    const int swz  = (id & 7) * 32 + (id >> 3);
    const int bn   = (swz & 7) * 256;          // 8 N-blocks
    const int bm   = (swz >> 3) * 256;         // 32 M-blocks
    const int srow = lane >> 2;                // staging: 16 rows / gload
    const int wrow = wid * 32;                 // this wave's 32-row staging slice
    // both-sides involution: physical 16B slot = logical slot ^ ((row>>1)&3)
    const int ssw  = ((lane & 3) ^ ((srow >> 1) & 3)) * 8;  // staged source k-off
    const int rsw  = (kq ^ ((l15 >> 1) & 3)) * 8;           // fragment read k-off

    f32x4 acc[8][4] = {};

#define STAGE(op, bufl, kh, tile, G, g0) do {                                        \
    gload16(G + (size_t)((g0) + wrow + srow)      * KD + (tile)*64 + (kh)*32 + ssw,  \
            &S[bufl][op][kh][(wrow)      * 32]);                                     \
    gload16(G + (size_t)((g0) + wrow + 16 + srow) * KD + (tile)*64 + (kh)*32 + ssw,  \
            &S[bufl][op][kh][(wrow + 16) * 32]);                                     \
  } while (0)

#define BAR()  asm volatile("s_barrier" ::: "memory")
#define VM4()  asm volatile("s_waitcnt vmcnt(4)" ::: "memory")
#define VM0()  asm volatile("s_waitcnt vmcnt(0)" ::: "memory")
#define LGK0() asm volatile("s_waitcnt lgkmcnt(0)" ::: "memory")
#define SB()   __builtin_amdgcn_sched_barrier(0)
#define PRI1() __builtin_amdgcn_s_setprio(1)
#define PRI0() __builtin_amdgcn_s_setprio(0)

#define FA(bufl, kh, m) (*(const short8*)&S[bufl][0][kh][(wr*128 + (m)*16 + l15)*32 + rsw])
#define FB(bufl, kh, n) (*(const short8*)&S[bufl][1][kh][(wc*64  + (n)*16 + l15)*32 + rsw])

#define MF(a_, b_, c_) __builtin_amdgcn_mfma_f32_16x16x32_bf16(a_, b_, c_, 0, 0, 0)

// operand-swapped: acc[m][n] += B^T-frag x A-frag -> D row=n-col-quad, col=m
#define MMROW(m, am)                                     \
    acc[m][0] = MF(bf0, am, acc[m][0]);                  \
    acc[m][1] = MF(bf1, am, acc[m][1]);                  \
    acc[m][2] = MF(bf2, am, acc[m][2]);                  \
    acc[m][3] = MF(bf3, am, acc[m][3])

// One phase: 12 ds_read_b128 + 2 stages + BAR + 32 MFMA + BAR.
#define PH(bufl, kh, STG, GATE) do {                                                  \
    short8 af0 = FA(bufl,kh,0), af1 = FA(bufl,kh,1), af2 = FA(bufl,kh,2),             \
           af3 = FA(bufl,kh,3), af4 = FA(bufl,kh,4), af5 = FA(bufl,kh,5),             \
           af6 = FA(bufl,kh,6), af7 = FA(bufl,kh,7);                                  \
    short8 bf0 = FB(bufl,kh,0), bf1 = FB(bufl,kh,1),                                  \
           bf2 = FB(bufl,kh,2), bf3 = FB(bufl,kh,3);                                  \
    STG; BAR(); SB(); PRI1();                                                         \
    MMROW(0, af0); MMROW(1, af1); MMROW(2, af2); MMROW(3, af3);                       \
    MMROW(4, af4); MMROW(5, af5); MMROW(6, af6); MMROW(7, af7);                       \
    PRI0(); SB(); LGK0(); GATE; BAR();                                                \
  } while (0)

    // ---- prologue: t0 full (buf0, 4 stages) + t1 kh0 (buf1, 2 stages)
    STAGE(0, 0, 0, 0, A,  bm); STAGE(1, 0, 0, 0, BT, bn);
    STAGE(0, 0, 1, 0, A,  bm); STAGE(1, 0, 1, 0, BT, bn);
    STAGE(1, 1, 0, 1, BT, bn); STAGE(0, 1, 0, 1, A,  bm);
    VM4();   // drain t0's 8 loads; t1-kh0's 4 stay in flight
    BAR();

    const int NITER = KD / 128;                // 16
    for (int it = 0; it < NITER - 1; ++it) {
        const int t2 = 2 * it + 2, t3 = 2 * it + 3;
        PH(0, 0, STAGE(1,1,1,t3-2,BT,bn); STAGE(0,1,1,t3-2,A,bm), );
        PH(0, 1, STAGE(1,0,0,t2,BT,bn);   STAGE(0,0,0,t2,A,bm),   VM4());
        PH(1, 0, STAGE(1,0,1,t2,BT,bn);   STAGE(0,0,1,t2,A,bm),   );
        PH(1, 1, STAGE(1,1,0,t3,BT,bn);   STAGE(0,1,0,t3,A,bm),   VM4());
    }
    // ---- tail: tiles 30 (buf0), 31 (buf1); only t31-kh1 still to stage
    PH(0, 0, STAGE(1,1,1,31,BT,bn); STAGE(0,1,1,31,A,bm), );
    PH(0, 1, , VM0());
    PH(1, 0, , );
    PH(1, 1, , );

    // ---- epilogue (swapped layout): lane covers row m = l15, cols kq*4..+3
    const float sc = EPI ? scaling[0] : 0.f;
#pragma unroll
    for (int m = 0; m < 8; ++m) {
        const size_t grow = (size_t)(bm + wr * 128 + m * 16 + l15);
#pragma unroll
        for (int n = 0; n < 4; ++n) {
            const int gcol = bn + wc * 64 + n * 16 + kq * 4;
            if constexpr (EPI) {
                const float4 bv = *reinterpret_cast<const float4*>(bias + gcol);
                float4 v;
                v.x = fmaxf(fmaf(sc, acc[m][n][0], bv.x), 0.f);
                v.y = fmaxf(fmaf(sc, acc[m][n][1], bv.y), 0.f);
                v.z = fmaxf(fmaf(sc, acc[m][n][2], bv.z), 0.f);
                v.w = fmaxf(fmaf(sc, acc[m][n][3], bv.w), 0.f);
                *reinterpret_cast<float4*>((float*)Cout + grow * ND + gcol) = v;
            } else {
                ushort4 v;
                v.x = f2b(acc[m][n][0]); v.y = f2b(acc[m][n][1]);
                v.z = f2b(acc[m][n][2]); v.w = f2b(acc[m][n][3]);
                *reinterpret_cast<ushort4*>((ushort*)Cout + grow * ND + gcol) = v;
            }
        }
    }
#undef STAGE
#undef PH
#undef MF
#undef MMROW
#undef FA
#undef FB
}

extern "C" void kernel_launch(void* const* d_in, const int* in_sizes, int n_in,
                              void* d_out, int out_size, void* d_ws, size_t ws_size,
                              hipStream_t stream)
{
    // inputs: x, k0, k1, k2, m0, m1, m2, scaling, bias
    const float* x    = (const float*)d_in[0];
    const float* k0w  = (const float*)d_in[1];
    const float* k1w  = (const float*)d_in[2];
    const float* k2w  = (const float*)d_in[3];
    const float* m0w  = (const float*)d_in[4];
    const float* m1w  = (const float*)d_in[5];
    const float* m2w  = (const float*)d_in[6];
    const float* sc   = (const float*)d_in[7];
    const float* bias = (const float*)d_in[8];

    const int Md = in_sizes[0] / KD;               // 8192
    const size_t NE = (size_t)Md * KD;             // 16.7M elems

    // d_out (64MB fp32): [act1 bf16 32MB][x_bf16 32MB]; GEMM3 overwrites all.
    ushort* act1 = (ushort*)d_out;
    ushort* xb   = (ushort*)d_out + NE;
    float*  out  = (float*)d_out;
    // ws: [act2 bf16 32MB][wbT0 8MB][wbT1 8MB][wbT2 8MB] = 56MB
    ushort* act2 = (ushort*)d_ws;
    ushort* wbT  = (ushort*)d_ws + NE;

    dim3 bl(256);
    dim3 gX(NE / (256 * 8));                       // 8192
    dim3 gT(KD / 32, ND / 32, 3);                  // (64,64,3)
    dim3 gG((ND / 256) * (Md / 256)), bG(512);     // 256 blocks 1D (XCD swizzle inside)

    convx <<<gX, bl, 0, stream>>>(x, xb);
    convT3<<<gT, bl, 0, stream>>>(k0w, k1w, k2w, m0w, m1w, m2w, wbT);

    gemm256<0><<<gG, bG, 0, stream>>>(xb,   wbT,                     act1, nullptr, nullptr);
    gemm256<0><<<gG, bG, 0, stream>>>(act1, wbT + (size_t)KD * ND,     act2, nullptr, nullptr);
    gemm256<1><<<gG, bG, 0, stream>>>(act2, wbT + (size_t)2 * KD * ND, out,  sc, bias);
}

// Round 10
// 210.863 us; speedup vs baseline: 1.2430x; 1.0686x over previous
//
#include <hip/hip_runtime.h>
#include <hip/hip_bf16.h>

// SparseFactorisationDense: out = relu(scaling * (x @ (k0*m0) @ (k1*m1) @ (k2*m2)) + bias)
// B=8192, D=U=2048.
// R10 = R9 with the LDS-read/MFMA overlap fix:
//   - fragment reads reordered into a dependency ladder (bf0, af0, bf1..bf3,
//     af1..af7) so the first MFMA depends on reads #1-2, not #12 -> compiler
//     emits counted lgkmcnt and MFMA overlaps the remaining LDS service
//   - pre-MFMA barrier removed (redundant per stage ledger: end-of-phase
//     LGK0+BAR already orders readers vs. next stage-DMA; VM gates per-wave)
//   - everything else identical to R9: 16x16 MFMA operand-swapped, slot-XOR
//     LDS swizzle (0 conflicts), T1 XCD swizzle, gload_lds staging, vmcnt(4)
//     gates, packed epilogue
//
// Stage ledger (iteration it, t1=2it+1, t2=2it+2, t3=2it+3), unchanged:
//   P(0,0) reads buf0-kh0; stages t1h1 -> buf1-kh1 (last read: prev P(1,1))
//   P(0,1) reads buf0-kh1; stages t2h0 -> buf0-kh0 (read P(0,0)); VM4 drains t1
//   P(1,0) reads buf1-kh0; stages t2h1 -> buf0-kh1 (read P(0,1))
//   P(1,1) reads buf1-kh1; stages t3h0 -> buf1-kh0 (read P(1,0)); VM4 drains t2
//   Every stage target's last read is >=1 barrier earlier (reader LGK0 first).

typedef __attribute__((ext_vector_type(8))) short  short8;
typedef __attribute__((ext_vector_type(8))) ushort ushort8v;
typedef __attribute__((ext_vector_type(4))) float  f32x4;

#define KD 2048
#define ND 2048

__device__ __forceinline__ ushort f2b(float f) {      // fp32 -> bf16 RNE
    union { float f; unsigned u; } v; v.f = f;
    unsigned r = v.u + 0x7fffu + ((v.u >> 16) & 1u);
    return (ushort)(r >> 16);
}

__device__ __forceinline__ void gload16(const ushort* g, ushort* l) {
    __builtin_amdgcn_global_load_lds(
        (const __attribute__((address_space(1))) void*)g,
        (__attribute__((address_space(3))) void*)l, 16, 0, 0);
}

// ---- x: fp32 -> bf16, 8 elems/thread
__global__ __launch_bounds__(256)
void convx(const float* __restrict__ x, ushort* __restrict__ xb)
{
    const size_t i = (size_t)blockIdx.x * 256 + threadIdx.x;
    const float4* src = reinterpret_cast<const float4*>(x) + i * 2;
    const float4 f0 = src[0], f1 = src[1];
    ushort8v u;
    u[0]=f2b(f0.x); u[1]=f2b(f0.y); u[2]=f2b(f0.z); u[3]=f2b(f0.w);
    u[4]=f2b(f1.x); u[5]=f2b(f1.y); u[6]=f2b(f1.z); u[7]=f2b(f1.w);
    reinterpret_cast<ushort8v*>(xb)[i] = u;
}

// ---- masked-weight transpose+convert for all 3 layers (blockIdx.z picks layer)
__global__ __launch_bounds__(256)
void convT3(const float* __restrict__ k0w, const float* __restrict__ k1w,
            const float* __restrict__ k2w, const float* __restrict__ m0w,
            const float* __restrict__ m1w, const float* __restrict__ m2w,
            ushort* __restrict__ wbT)
{
    const int z = blockIdx.z;
    const float* kw = z == 0 ? k0w : (z == 1 ? k1w : k2w);
    const float* mw = z == 0 ? m0w : (z == 1 ? m1w : m2w);
    ushort* o = wbT + (size_t)z * KD * ND;

    __shared__ ushort t[32][36];
    const int tid = threadIdx.x;
    const int bk = blockIdx.x * 32, bn = blockIdx.y * 32;
    {
        const int r = tid >> 3, c = (tid & 7) * 4;
        const size_t g = (size_t)(bk + r) * ND + bn + c;
        const float4 kv = *reinterpret_cast<const float4*>(kw + g);
        const float4 mv = *reinterpret_cast<const float4*>(mw + g);
        t[r][c + 0] = f2b(kv.x * mv.x);
        t[r][c + 1] = f2b(kv.y * mv.y);
        t[r][c + 2] = f2b(kv.z * mv.z);
        t[r][c + 3] = f2b(kv.w * mv.w);
    }
    __syncthreads();
    {
        const int n = tid >> 3, kq = (tid & 7) * 4;
        ushort4 ov;
        ov.x = t[kq + 0][n]; ov.y = t[kq + 1][n];
        ov.z = t[kq + 2][n]; ov.w = t[kq + 3][n];
        *reinterpret_cast<ushort4*>(&o[(size_t)(bn + n) * KD + bk + kq]) = ov;
    }
}

// ================= 256x256 merged-phase GEMM (16x16 MFMA) =================
// C[M][N] = A[M][K] @ BT[N][K]^T, all bf16 in, fp32 accum.
template<int EPI>
__global__ __launch_bounds__(512, 2)
void gemm256(const ushort* __restrict__ A, const ushort* __restrict__ BT,
             void* __restrict__ Cout,
             const float* __restrict__ scaling, const float* __restrict__ bias)
{
    // [buf][op 0=A 1=B][kh][row*32 + k]  = 128 KiB
    __shared__ ushort S[2][2][2][256 * 32];

    const int tid  = threadIdx.x;
    const int lane = tid & 63;
    const int wid  = tid >> 6;                 // 0..7
    const int wr   = wid >> 2, wc = wid & 3;   // 2x4 wave grid: 128x64 per wave
    const int l15  = lane & 15;
    const int kq   = lane >> 4;                // fragment k-slot 0..3
    // T1: bijective XCD swizzle (256 blocks % 8 XCDs == 0)
    const int id   = blockIdx.x;
    const int swz  = (id & 7) * 32 + (id >> 3);
    const int bn   = (swz & 7) * 256;          // 8 N-blocks
    const int bm   = (swz >> 3) * 256;         // 32 M-blocks
    const int srow = lane >> 2;                // staging: 16 rows / gload
    const int wrow = wid * 32;                 // this wave's 32-row staging slice
    // both-sides involution: physical 16B slot = logical slot ^ ((row>>1)&3)
    const int ssw  = ((lane & 3) ^ ((srow >> 1) & 3)) * 8;  // staged source k-off
    const int rsw  = (kq ^ ((l15 >> 1) & 3)) * 8;           // fragment read k-off

    f32x4 acc[8][4] = {};

#define STAGE(op, bufl, kh, tile, G, g0) do {                                        \
    gload16(G + (size_t)((g0) + wrow + srow)      * KD + (tile)*64 + (kh)*32 + ssw,  \
            &S[bufl][op][kh][(wrow)      * 32]);                                     \
    gload16(G + (size_t)((g0) + wrow + 16 + srow) * KD + (tile)*64 + (kh)*32 + ssw,  \
            &S[bufl][op][kh][(wrow + 16) * 32]);                                     \
  } while (0)

#define BAR()  asm volatile("s_barrier" ::: "memory")
#define VM4()  asm volatile("s_waitcnt vmcnt(4)" ::: "memory")
#define VM0()  asm volatile("s_waitcnt vmcnt(0)" ::: "memory")
#define LGK0() asm volatile("s_waitcnt lgkmcnt(0)" ::: "memory")
#define SB()   __builtin_amdgcn_sched_barrier(0)
#define PRI1() __builtin_amdgcn_s_setprio(1)
#define PRI0() __builtin_amdgcn_s_setprio(0)

#define FA(bufl, kh, m) (*(const short8*)&S[bufl][0][kh][(wr*128 + (m)*16 + l15)*32 + rsw])
#define FB(bufl, kh, n) (*(const short8*)&S[bufl][1][kh][(wc*64  + (n)*16 + l15)*32 + rsw])

#define MF(a_, b_, c_) __builtin_amdgcn_mfma_f32_16x16x32_bf16(a_, b_, c_, 0, 0, 0)

// operand-swapped: acc[m][n] += B^T-frag x A-frag -> D row=n-col-quad, col=m
#define MMROW(m, am)                                     \
    acc[m][0] = MF(bf0, am, acc[m][0]);                  \
    acc[m][1] = MF(bf1, am, acc[m][1]);                  \
    acc[m][2] = MF(bf2, am, acc[m][2]);                  \
    acc[m][3] = MF(bf3, am, acc[m][3])

// One phase: 12 ds_read_b128 in LADDER order + 2 stages + 32 MFMA + BAR.
// Ladder: first MFMA depends on reads #1-2 -> counted lgkmcnt, LDS service
// overlaps the MFMA burst (within-wave and cross-wave).
#define PH(bufl, kh, STG, GATE) do {                                                  \
    short8 bf0 = FB(bufl,kh,0);                                                       \
    short8 af0 = FA(bufl,kh,0);                                                       \
    short8 bf1 = FB(bufl,kh,1), bf2 = FB(bufl,kh,2), bf3 = FB(bufl,kh,3);             \
    short8 af1 = FA(bufl,kh,1), af2 = FA(bufl,kh,2), af3 = FA(bufl,kh,3),             \
           af4 = FA(bufl,kh,4), af5 = FA(bufl,kh,5), af6 = FA(bufl,kh,6),             \
           af7 = FA(bufl,kh,7);                                                       \
    STG;                                                                              \
    PRI1();                                                                           \
    MMROW(0, af0); MMROW(1, af1); MMROW(2, af2); MMROW(3, af3);                       \
    MMROW(4, af4); MMROW(5, af5); MMROW(6, af6); MMROW(7, af7);                       \
    PRI0(); SB(); LGK0(); GATE; BAR();                                                \
  } while (0)

    // ---- prologue: t0 full (buf0, 4 stages) + t1 kh0 (buf1, 2 stages)
    STAGE(0, 0, 0, 0, A,  bm); STAGE(1, 0, 0, 0, BT, bn);
    STAGE(0, 0, 1, 0, A,  bm); STAGE(1, 0, 1, 0, BT, bn);
    STAGE(1, 1, 0, 1, BT, bn); STAGE(0, 1, 0, 1, A,  bm);
    VM4();   // drain t0's 8 loads; t1-kh0's 4 stay in flight
    BAR();

    const int NITER = KD / 128;                // 16
    for (int it = 0; it < NITER - 1; ++it) {
        const int t1 = 2 * it + 1, t2 = 2 * it + 2, t3 = 2 * it + 3;
        PH(0, 0, STAGE(1,1,1,t1,BT,bn); STAGE(0,1,1,t1,A,bm), );
        PH(0, 1, STAGE(1,0,0,t2,BT,bn); STAGE(0,0,0,t2,A,bm), VM4());
        PH(1, 0, STAGE(1,0,1,t2,BT,bn); STAGE(0,0,1,t2,A,bm), );
        PH(1, 1, STAGE(1,1,0,t3,BT,bn); STAGE(0,1,0,t3,A,bm), VM4());
    }
    // ---- tail: tiles 30 (buf0), 31 (buf1); only t31-kh1 still to stage
    PH(0, 0, STAGE(1,1,1,31,BT,bn); STAGE(0,1,1,31,A,bm), );
    PH(0, 1, , VM0());
    PH(1, 0, , );
    PH(1, 1, , );

    // ---- epilogue (swapped layout): lane covers row m = l15, cols kq*4..+3
    const float sc = EPI ? scaling[0] : 0.f;
#pragma unroll
    for (int m = 0; m < 8; ++m) {
        const size_t grow = (size_t)(bm + wr * 128 + m * 16 + l15);
#pragma unroll
        for (int n = 0; n < 4; ++n) {
            const int gcol = bn + wc * 64 + n * 16 + kq * 4;
            if constexpr (EPI) {
                const float4 bv = *reinterpret_cast<const float4*>(bias + gcol);
                float4 v;
                v.x = fmaxf(fmaf(sc, acc[m][n][0], bv.x), 0.f);
                v.y = fmaxf(fmaf(sc, acc[m][n][1], bv.y), 0.f);
                v.z = fmaxf(fmaf(sc, acc[m][n][2], bv.z), 0.f);
                v.w = fmaxf(fmaf(sc, acc[m][n][3], bv.w), 0.f);
                *reinterpret_cast<float4*>((float*)Cout + grow * ND + gcol) = v;
            } else {
                ushort4 v;
                v.x = f2b(acc[m][n][0]); v.y = f2b(acc[m][n][1]);
                v.z = f2b(acc[m][n][2]); v.w = f2b(acc[m][n][3]);
                *reinterpret_cast<ushort4*>((ushort*)Cout + grow * ND + gcol) = v;
            }
        }
    }
#undef STAGE
#undef PH
#undef MF
#undef MMROW
#undef FA
#undef FB
}

extern "C" void kernel_launch(void* const* d_in, const int* in_sizes, int n_in,
                              void* d_out, int out_size, void* d_ws, size_t ws_size,
                              hipStream_t stream)
{
    // inputs: x, k0, k1, k2, m0, m1, m2, scaling, bias
    const float* x    = (const float*)d_in[0];
    const float* k0w  = (const float*)d_in[1];
    const float* k1w  = (const float*)d_in[2];
    const float* k2w  = (const float*)d_in[3];
    const float* m0w  = (const float*)d_in[4];
    const float* m1w  = (const float*)d_in[5];
    const float* m2w  = (const float*)d_in[6];
    const float* sc   = (const float*)d_in[7];
    const float* bias = (const float*)d_in[8];

    const int Md = in_sizes[0] / KD;               // 8192
    const size_t NE = (size_t)Md * KD;             // 16.7M elems

    // d_out (64MB fp32): [act1 bf16 32MB][x_bf16 32MB]; GEMM3 overwrites all.
    ushort* act1 = (ushort*)d_out;
    ushort* xb   = (ushort*)d_out + NE;
    float*  out  = (float*)d_out;
    // ws: [act2 bf16 32MB][wbT0 8MB][wbT1 8MB][wbT2 8MB] = 56MB
    ushort* act2 = (ushort*)d_ws;
    ushort* wbT  = (ushort*)d_ws + NE;

    dim3 bl(256);
    dim3 gX(NE / (256 * 8));                       // 8192
    dim3 gT(KD / 32, ND / 32, 3);                  // (64,64,3)
    dim3 gG((ND / 256) * (Md / 256)), bG(512);     // 256 blocks 1D (XCD swizzle inside)

    convx <<<gX, bl, 0, stream>>>(x, xb);
    convT3<<<gT, bl, 0, stream>>>(k0w, k1w, k2w, m0w, m1w, m2w, wbT);

    gemm256<0><<<gG, bG, 0, stream>>>(xb,   wbT,                     act1, nullptr, nullptr);
    gemm256<0><<<gG, bG, 0, stream>>>(act1, wbT + (size_t)KD * ND,     act2, nullptr, nullptr);
    gemm256<1><<<gG, bG, 0, stream>>>(act2, wbT + (size_t)2 * KD * ND, out,  sc, bias);
}